// Round 6
// baseline (343.054 us; speedup 1.0000x reference)
//
#include <hip/hip_runtime.h>
#include <hip/hip_bf16.h>
#include <stdint.h>

#define T_TOK 2048
#define DIM 1024
#define FDIM 2048
#define NEXP 8
#define NSLOT 4096
#define MAXTILE 64

typedef short bf16x8 __attribute__((ext_vector_type(8)));
typedef float f32x4 __attribute__((ext_vector_type(4)));

__device__ __forceinline__ unsigned short f2bf(float f) {
  union { float f; unsigned int u; } v; v.f = f;
  unsigned int r = v.u + 0x7FFFu + ((v.u >> 16) & 1u);
  return (unsigned short)(r >> 16);
}

__device__ __forceinline__ void gld_lds16(const void* g, void* l) {
  __builtin_amdgcn_global_load_lds(
      (const __attribute__((address_space(1))) unsigned int*)g,
      (__attribute__((address_space(3))) unsigned int*)l, 16, 0, 0);
}

// ---------------- Router: fp32 exact, one wave per token ----------------
__global__ void router_kernel(const float* __restrict__ x, const float* __restrict__ rk,
                              int* __restrict__ counts, int* __restrict__ tok_e,
                              float* __restrict__ tok_w) {
  int w = threadIdx.x >> 6, lane = threadIdx.x & 63;
  int t = blockIdx.x * 4 + w;
  float acc[NEXP];
#pragma unroll
  for (int e = 0; e < NEXP; ++e) acc[e] = 0.f;
  const float4* xr = (const float4*)(x + (size_t)t * DIM);
#pragma unroll
  for (int i = 0; i < 4; ++i) {
    float4 xv = xr[i * 64 + lane];
    int d0 = (i * 64 + lane) * 4;
#pragma unroll
    for (int j = 0; j < 4; ++j) {
      const float4* rr = (const float4*)(rk + (size_t)(d0 + j) * NEXP);
      float4 r0 = rr[0], r1 = rr[1];
      float xs = (j == 0) ? xv.x : (j == 1) ? xv.y : (j == 2) ? xv.z : xv.w;
      acc[0] += xs * r0.x; acc[1] += xs * r0.y; acc[2] += xs * r0.z; acc[3] += xs * r0.w;
      acc[4] += xs * r1.x; acc[5] += xs * r1.y; acc[6] += xs * r1.z; acc[7] += xs * r1.w;
    }
  }
#pragma unroll
  for (int off = 32; off > 0; off >>= 1) {
#pragma unroll
    for (int e = 0; e < NEXP; ++e) acc[e] += __shfl_xor(acc[e], off, 64);
  }
  if (lane == 0) {
    float m = acc[0];
    for (int e = 1; e < NEXP; ++e) m = fmaxf(m, acc[e]);
    float p[NEXP], s = 0.f;
    for (int e = 0; e < NEXP; ++e) { p[e] = expf(acc[e] - m); s += p[e]; }
    float inv = 1.f / s;
    for (int e = 0; e < NEXP; ++e) p[e] *= inv;
    int i1 = 0;
    for (int e = 1; e < NEXP; ++e) if (p[e] > p[i1]) i1 = e;      // ties -> lowest idx
    int i2 = (i1 == 0) ? 1 : 0;
    for (int e = 0; e < NEXP; ++e) if (e != i1 && p[e] > p[i2]) i2 = e;
    // reference: softmax over the two top PROBABILITIES
    float e1 = expf(p[i1]), e2 = expf(p[i2]);
    float winv = 1.f / (e1 + e2);
    tok_e[t * 2] = i1; tok_e[t * 2 + 1] = i2;
    tok_w[t * 2] = e1 * winv; tok_w[t * 2 + 1] = e2 * winv;
    atomicAdd(&counts[i1], 1); atomicAdd(&counts[i2], 1);
  }
}

__global__ void scan_kernel(const int* __restrict__ counts, int* __restrict__ offsets,
                            int* __restrict__ tile_e, int* __restrict__ tile_mt,
                            int* __restrict__ ntiles) {
  if (threadIdx.x == 0) {
    int s = 0, t = 0;
    for (int e = 0; e < NEXP; ++e) {
      offsets[e] = s; s += counts[e];
      int nt = (counts[e] + 127) >> 7;
      for (int m = 0; m < nt; ++m) { tile_e[t] = e; tile_mt[t] = m; ++t; }
    }
    ntiles[0] = t;
  }
}

__global__ void assign_kernel(const int* __restrict__ tok_e, const float* __restrict__ tok_w,
                              const int* __restrict__ offsets, int* __restrict__ cursor,
                              int* __restrict__ slot_token, float* __restrict__ slot_weight,
                              int* __restrict__ tok_slot) {
  int t = blockIdx.x * 256 + threadIdx.x;
  if (t >= T_TOK) return;
#pragma unroll
  for (int k = 0; k < 2; ++k) {
    int e = tok_e[t * 2 + k];
    int pos = atomicAdd(&cursor[e], 1);
    int slot = offsets[e] + pos;
    slot_token[slot] = t;
    slot_weight[slot] = tok_w[t * 2 + k];
    tok_slot[t * 2 + k] = slot;
  }
}

// ---------------- Conversions ----------------
__global__ void cvt_x_kernel(const float* __restrict__ x, unsigned short* __restrict__ xb) {
  int i = blockIdx.x * 256 + threadIdx.x;  // T*D/8 threads
  const float4* p = (const float4*)x;
  float4 a = p[i * 2], b = p[i * 2 + 1];
  uint4 o;
  o.x = ((unsigned)f2bf(a.y) << 16) | f2bf(a.x);
  o.y = ((unsigned)f2bf(a.w) << 16) | f2bf(a.z);
  o.z = ((unsigned)f2bf(b.y) << 16) | f2bf(b.x);
  o.w = ((unsigned)f2bf(b.w) << 16) | f2bf(b.z);
  ((uint4*)xb)[i] = o;
}

// in fp32 [E][R][C] -> out bf16 [E][C][R]
__global__ void transpose_cvt_kernel(const float* __restrict__ in, unsigned short* __restrict__ out,
                                     int R, int C) {
  __shared__ float lds[64][65];
  int e = blockIdx.z;
  size_t base = (size_t)e * (size_t)R * (size_t)C;
  int rb = blockIdx.y * 64, cb = blockIdx.x * 64;
  int tid = threadIdx.x;
  int col4 = (tid & 15) * 4, row = tid >> 4;
#pragma unroll
  for (int it = 0; it < 4; ++it) {
    int r = row + it * 16;
    float4 v = *(const float4*)(in + base + (size_t)(rb + r) * C + cb + col4);
    lds[col4 + 0][r] = v.x; lds[col4 + 1][r] = v.y;
    lds[col4 + 2][r] = v.z; lds[col4 + 3][r] = v.w;
  }
  __syncthreads();
  int r2 = (tid & 31) * 2, c = tid >> 5;
#pragma unroll
  for (int it = 0; it < 8; ++it) {
    int cc = c + it * 8;
    unsigned v = ((unsigned)f2bf(lds[cc][r2 + 1]) << 16) | f2bf(lds[cc][r2]);
    *(unsigned*)(out + base + (size_t)(cb + cc) * R + rb + r2) = v;
  }
}

// ================= ABLATION PROBES (round 6) =================
// Bisect gemm_gateup's 113us: same 512-block grid, same per-step barrier
// structure, same resource class. Outputs go to fuse/part scratch which the
// real GEMMs fully overwrite afterwards -> final output unchanged.

// Staging half only: 12 gld_lds/wave/step x 16 steps, 2 barriers/step.
__global__ __launch_bounds__(256) void probe_stage(
    const unsigned short* __restrict__ xb, const unsigned short* __restrict__ wg,
    const unsigned short* __restrict__ wu, const int* __restrict__ slot_token,
    unsigned int* __restrict__ pout) {
  __shared__ unsigned short Al[128 * 64];
  __shared__ unsigned short Bgl[128 * 64];
  __shared__ unsigned short Bul[128 * 64];
  int tid = threadIdx.x, w = tid >> 6, lane = tid & 63;
  int w4 = w * 4;
  int e = blockIdx.y >> 2, mt = blockIdx.y & 3;
  int nt = blockIdx.x;
  int csrc = ((lane & 7) ^ (lane >> 3)) * 8;
  const unsigned short* asrc[4];
  const unsigned short* bgsrc[4];
  const unsigned short* busrc[4];
#pragma unroll
  for (int ii = 0; ii < 4; ++ii) {
    int i = w4 + ii;
    int r = i * 8 + (lane >> 3);
    int row = mt * 128 + r;
    int tok = slot_token[(e * 512 + row) & (NSLOT - 1)];
    asrc[ii] = xb + (size_t)tok * DIM + csrc;
    size_t frow = (size_t)e * FDIM + (size_t)(nt * 128 + r);
    bgsrc[ii] = wg + frow * DIM + csrc;
    busrc[ii] = wu + frow * DIM + csrc;
  }
  for (int k0 = 0; k0 < DIM; k0 += 64) {
#pragma unroll
    for (int ii = 0; ii < 4; ++ii) {
      int i = w4 + ii;
      gld_lds16(asrc[ii] + k0, &Al[i * 512]);
      gld_lds16(bgsrc[ii] + k0, &Bgl[i * 512]);
      gld_lds16(busrc[ii] + k0, &Bul[i * 512]);
    }
    __syncthreads();
    // (compute omitted)
    __syncthreads();
  }
  if (tid == 0)
    pout[blockIdx.x + 16 * blockIdx.y] =
        (unsigned)Al[0] + (unsigned)Bgl[0] + (unsigned)Bul[0];
}

// Compute half only: stage once, then 16 steps of 24 ds_read_b128 + 64 MFMA.
__global__ __launch_bounds__(256) void probe_mfma(
    const unsigned short* __restrict__ xb, const unsigned short* __restrict__ wg,
    const unsigned short* __restrict__ wu, const int* __restrict__ slot_token,
    float* __restrict__ pout) {
  __shared__ unsigned short Al[128 * 64];
  __shared__ unsigned short Bgl[128 * 64];
  __shared__ unsigned short Bul[128 * 64];
  int tid = threadIdx.x, w = tid >> 6, lane = tid & 63;
  int w4 = w * 4;
  int e = blockIdx.y >> 2, mt = blockIdx.y & 3;
  int nt = blockIdx.x;
  int csrc = ((lane & 7) ^ (lane >> 3)) * 8;
#pragma unroll
  for (int ii = 0; ii < 4; ++ii) {
    int i = w4 + ii;
    int r = i * 8 + (lane >> 3);
    int row = mt * 128 + r;
    int tok = slot_token[(e * 512 + row) & (NSLOT - 1)];
    gld_lds16(xb + (size_t)tok * DIM + csrc, &Al[i * 512]);
    size_t frow = (size_t)e * FDIM + (size_t)(nt * 128 + r);
    gld_lds16(wg + frow * DIM + csrc, &Bgl[i * 512]);
    gld_lds16(wu + frow * DIM + csrc, &Bul[i * 512]);
  }
  f32x4 accg[4][4] = {};
  f32x4 accu[4][4] = {};
  int wr = (w >> 1) * 64, wc = (w & 1) * 64;
  int swz = (lane & 7) << 3;
  int kof0 = ((lane >> 4) * 8) ^ swz;
  int kof1 = (32 + (lane >> 4) * 8) ^ swz;
  __syncthreads();
  for (int k0 = 0; k0 < DIM; k0 += 64) {
#pragma unroll
    for (int kk = 0; kk < 2; ++kk) {
      int kof = kk ? kof1 : kof0;
      bf16x8 af[4], bg[4], bu[4];
#pragma unroll
      for (int q = 0; q < 4; ++q) {
        af[q] = *(const bf16x8*)&Al[(wr + q * 16 + (lane & 15)) * 64 + kof];
        bg[q] = *(const bf16x8*)&Bgl[(wc + q * 16 + (lane & 15)) * 64 + kof];
        bu[q] = *(const bf16x8*)&Bul[(wc + q * 16 + (lane & 15)) * 64 + kof];
      }
#pragma unroll
      for (int m4 = 0; m4 < 4; ++m4) {
#pragma unroll
        for (int n4 = 0; n4 < 4; ++n4) {
          accg[m4][n4] = __builtin_amdgcn_mfma_f32_16x16x32_bf16(af[m4], bg[n4], accg[m4][n4], 0, 0, 0);
          accu[m4][n4] = __builtin_amdgcn_mfma_f32_16x16x32_bf16(af[m4], bu[n4], accu[m4][n4], 0, 0, 0);
        }
      }
    }
    __syncthreads();
    __syncthreads();
  }
  float s = 0.f;
#pragma unroll
  for (int m4 = 0; m4 < 4; ++m4)
#pragma unroll
    for (int n4 = 0; n4 < 4; ++n4)
#pragma unroll
      for (int j = 0; j < 4; ++j) s += accg[m4][n4][j] + accu[m4][n4][j];
  pout[(size_t)(blockIdx.x + 16 * blockIdx.y) * 256 + tid] = s;
}

// ---------------- Pass A: fuse[slot][F] = silu(X@Wg) * (X@Wu), grouped per expert ----------------
__global__ __launch_bounds__(256) void gemm_gateup(
    const unsigned short* __restrict__ xb, const unsigned short* __restrict__ wg,
    const unsigned short* __restrict__ wu, const int* __restrict__ counts,
    const int* __restrict__ offsets, const int* __restrict__ slot_token,
    const int* __restrict__ tile_e, const int* __restrict__ tile_mt,
    const int* __restrict__ ntiles, unsigned short* __restrict__ fuse) {
  int ys = blockIdx.y;
  if (ys >= ntiles[0]) return;
  int e = tile_e[ys], mt = tile_mt[ys];
  int cnt = counts[e];
  int off = offsets[e];
  int nt = blockIdx.x;
  __shared__ unsigned short Al[128 * 64];
  __shared__ unsigned short Bgl[128 * 64];
  __shared__ unsigned short Bul[128 * 64];
  int tid = threadIdx.x, w = tid >> 6, lane = tid & 63;
  int w4 = w * 4;
  int csrc = ((lane & 7) ^ (lane >> 3)) * 8;  // swizzled source chunk (bf16 elems)
  const unsigned short* asrc[4];
  const unsigned short* bgsrc[4];
  const unsigned short* busrc[4];
#pragma unroll
  for (int ii = 0; ii < 4; ++ii) {
    int i = w4 + ii;
    int r = i * 8 + (lane >> 3);
    int row = mt * 128 + r;
    int tok = (row < cnt) ? slot_token[off + row] : 0;  // clamp: garbage rows computed, not written
    asrc[ii] = xb + (size_t)tok * DIM + csrc;
    size_t frow = (size_t)e * FDIM + (size_t)(nt * 128 + r);
    bgsrc[ii] = wg + frow * DIM + csrc;
    busrc[ii] = wu + frow * DIM + csrc;
  }
  f32x4 accg[4][4] = {};
  f32x4 accu[4][4] = {};
  int wr = (w >> 1) * 64, wc = (w & 1) * 64;
  int swz = (lane & 7) << 3;
  int kof0 = ((lane >> 4) * 8) ^ swz;        // kk=0 swizzled col offset
  int kof1 = (32 + (lane >> 4) * 8) ^ swz;   // kk=1
  for (int k0 = 0; k0 < DIM; k0 += 64) {
#pragma unroll
    for (int ii = 0; ii < 4; ++ii) {
      int i = w4 + ii;
      gld_lds16(asrc[ii] + k0, &Al[i * 512]);
      gld_lds16(bgsrc[ii] + k0, &Bgl[i * 512]);
      gld_lds16(busrc[ii] + k0, &Bul[i * 512]);
    }
    __syncthreads();
#pragma unroll
    for (int kk = 0; kk < 2; ++kk) {
      int kof = kk ? kof1 : kof0;
      bf16x8 af[4], bg[4], bu[4];
#pragma unroll
      for (int q = 0; q < 4; ++q) {
        af[q] = *(const bf16x8*)&Al[(wr + q * 16 + (lane & 15)) * 64 + kof];
        bg[q] = *(const bf16x8*)&Bgl[(wc + q * 16 + (lane & 15)) * 64 + kof];
        bu[q] = *(const bf16x8*)&Bul[(wc + q * 16 + (lane & 15)) * 64 + kof];
      }
#pragma unroll
      for (int m4 = 0; m4 < 4; ++m4) {
#pragma unroll
        for (int n4 = 0; n4 < 4; ++n4) {
          accg[m4][n4] = __builtin_amdgcn_mfma_f32_16x16x32_bf16(af[m4], bg[n4], accg[m4][n4], 0, 0, 0);
          accu[m4][n4] = __builtin_amdgcn_mfma_f32_16x16x32_bf16(af[m4], bu[n4], accu[m4][n4], 0, 0, 0);
        }
      }
    }
    __syncthreads();
  }
#pragma unroll
  for (int m4 = 0; m4 < 4; ++m4) {
#pragma unroll
    for (int n4 = 0; n4 < 4; ++n4) {
      f32x4 g = accg[m4][n4], u = accu[m4][n4];
#pragma unroll
      for (int j = 0; j < 4; ++j) {
        int r = wr + m4 * 16 + (lane >> 4) * 4 + j;  // C layout: row=(lane>>4)*4+reg
        int row = mt * 128 + r;
        if (row < cnt) {
          float gv = g[j];
          float val = gv / (1.f + expf(-gv)) * u[j];
          int f = nt * 128 + wc + n4 * 16 + (lane & 15);  // col=lane&15
          fuse[(size_t)(off + row) * FDIM + f] = f2bf(val);
        }
      }
    }
  }
}

// ---------------- Pass B: part[slot][D] = w_slot * (fuse @ WdT) ----------------
__global__ __launch_bounds__(256) void gemm_down(
    const unsigned short* __restrict__ fuse, const unsigned short* __restrict__ wd,
    const int* __restrict__ counts, const int* __restrict__ offsets,
    const float* __restrict__ slot_weight, const int* __restrict__ tile_e,
    const int* __restrict__ tile_mt, const int* __restrict__ ntiles,
    float* __restrict__ part) {
  int ys = blockIdx.y;
  if (ys >= ntiles[0]) return;
  int e = tile_e[ys], mt = tile_mt[ys];
  int cnt = counts[e];
  int off = offsets[e];
  int nt = blockIdx.x;  // over D/128 = 8
  __shared__ unsigned short Al[128 * 64];
  __shared__ unsigned short Bl[128 * 64];
  int tid = threadIdx.x, w = tid >> 6, lane = tid & 63;
  int w4 = w * 4;
  int csrc = ((lane & 7) ^ (lane >> 3)) * 8;
  const unsigned short* asrc[4];
  const unsigned short* bsrc[4];
#pragma unroll
  for (int ii = 0; ii < 4; ++ii) {
    int i = w4 + ii;
    int r = i * 8 + (lane >> 3);
    int row = mt * 128 + r;
    int grow = (row < cnt) ? (off + row) : off;  // clamp to valid memory
    asrc[ii] = fuse + (size_t)grow * FDIM + csrc;
    size_t drow = (size_t)e * DIM + (size_t)(nt * 128 + r);
    bsrc[ii] = wd + drow * FDIM + csrc;
  }
  f32x4 acc[4][4] = {};
  int wr = (w >> 1) * 64, wc = (w & 1) * 64;
  int swz = (lane & 7) << 3;
  int kof0 = ((lane >> 4) * 8) ^ swz;
  int kof1 = (32 + (lane >> 4) * 8) ^ swz;
  for (int k0 = 0; k0 < FDIM; k0 += 64) {
#pragma unroll
    for (int ii = 0; ii < 4; ++ii) {
      int i = w4 + ii;
      gld_lds16(asrc[ii] + k0, &Al[i * 512]);
      gld_lds16(bsrc[ii] + k0, &Bl[i * 512]);
    }
    __syncthreads();
#pragma unroll
    for (int kk = 0; kk < 2; ++kk) {
      int kof = kk ? kof1 : kof0;
      bf16x8 af[4], bfr[4];
#pragma unroll
      for (int q = 0; q < 4; ++q) {
        af[q] = *(const bf16x8*)&Al[(wr + q * 16 + (lane & 15)) * 64 + kof];
        bfr[q] = *(const bf16x8*)&Bl[(wc + q * 16 + (lane & 15)) * 64 + kof];
      }
#pragma unroll
      for (int m4 = 0; m4 < 4; ++m4) {
#pragma unroll
        for (int n4 = 0; n4 < 4; ++n4) {
          acc[m4][n4] = __builtin_amdgcn_mfma_f32_16x16x32_bf16(af[m4], bfr[n4], acc[m4][n4], 0, 0, 0);
        }
      }
    }
    __syncthreads();
  }
#pragma unroll
  for (int m4 = 0; m4 < 4; ++m4) {
#pragma unroll
    for (int j = 0; j < 4; ++j) {
      int r = wr + m4 * 16 + (lane >> 4) * 4 + j;
      int row = mt * 128 + r;
      if (row < cnt) {
        float wgt = slot_weight[off + row];
#pragma unroll
        for (int n4 = 0; n4 < 4; ++n4) {
          int d = nt * 128 + wc + n4 * 16 + (lane & 15);
          part[(size_t)(off + row) * DIM + d] = acc[m4][n4][j] * wgt;
        }
      }
    }
  }
}

// ---------------- Combine: out[t] = part[slot0] + part[slot1] ----------------
__global__ void combine_kernel(const float* __restrict__ part, const int* __restrict__ tok_slot,
                               float* __restrict__ out) {
  int i = blockIdx.x * 256 + threadIdx.x;  // T*D/4 threads
  int t = i >> 8;
  int c = i & 255;
  int s0 = tok_slot[t * 2], s1 = tok_slot[t * 2 + 1];
  float4 a = ((const float4*)(part + (size_t)s0 * DIM))[c];
  float4 b = ((const float4*)(part + (size_t)s1 * DIM))[c];
  float4 o;
  o.x = a.x + b.x; o.y = a.y + b.y; o.z = a.z + b.z; o.w = a.w + b.w;
  ((float4*)(out + (size_t)t * DIM))[c] = o;
}

extern "C" void kernel_launch(void* const* d_in, const int* in_sizes, int n_in,
                              void* d_out, int out_size, void* d_ws, size_t ws_size,
                              hipStream_t stream) {
  (void)in_sizes; (void)n_in; (void)out_size;
  const float* x    = (const float*)d_in[0];
  const float* rk   = (const float*)d_in[1];
  const float* wg_f = (const float*)d_in[2];
  const float* wu_f = (const float*)d_in[3];
  const float* wd_f = (const float*)d_in[4];
  float* out = (float*)d_out;

  char* ws = (char*)d_ws;
  size_t o_xb   = 0;
  size_t o_wg   = o_xb + (size_t)T_TOK * DIM * 2;
  size_t o_wu   = o_wg + (size_t)NEXP * FDIM * DIM * 2;
  size_t o_wd   = o_wu + (size_t)NEXP * FDIM * DIM * 2;
  size_t o_fuse = o_wd + (size_t)NEXP * DIM * FDIM * 2;
  size_t o_part = o_fuse + (size_t)NSLOT * FDIM * 2;
  size_t o_meta = o_part + (size_t)NSLOT * DIM * 4;
  size_t o_counts = o_meta;
  size_t o_cursor = o_counts + 32;
  size_t o_offs   = o_cursor + 32;
  size_t o_tok_e  = o_offs + 32;
  size_t o_tok_w  = o_tok_e + (size_t)T_TOK * 2 * 4;
  size_t o_tok_s  = o_tok_w + (size_t)T_TOK * 2 * 4;
  size_t o_st     = o_tok_s + (size_t)T_TOK * 2 * 4;
  size_t o_sw     = o_st + (size_t)NSLOT * 4;
  size_t o_te     = o_sw + (size_t)NSLOT * 4;
  size_t o_tm     = o_te + MAXTILE * 4;
  size_t o_ntl    = o_tm + MAXTILE * 4;
  size_t need     = o_ntl + 32;
  if (ws_size < need) return;  // diagnostic: absmax will equal ~0.785 (zero output)

  unsigned short* xb   = (unsigned short*)(ws + o_xb);
  unsigned short* wgt  = (unsigned short*)(ws + o_wg);
  unsigned short* wut  = (unsigned short*)(ws + o_wu);
  unsigned short* wdt  = (unsigned short*)(ws + o_wd);
  unsigned short* fuse = (unsigned short*)(ws + o_fuse);
  float* part          = (float*)(ws + o_part);
  int* counts          = (int*)(ws + o_counts);
  int* cursor          = (int*)(ws + o_cursor);
  int* offsets         = (int*)(ws + o_offs);
  int* tok_e           = (int*)(ws + o_tok_e);
  float* tok_w         = (float*)(ws + o_tok_w);
  int* tok_slot        = (int*)(ws + o_tok_s);
  int* slot_token      = (int*)(ws + o_st);
  float* slot_weight   = (float*)(ws + o_sw);
  int* tile_e          = (int*)(ws + o_te);
  int* tile_mt         = (int*)(ws + o_tm);
  int* ntiles          = (int*)(ws + o_ntl);

  hipMemsetAsync(ws + o_counts, 0, 64, stream);  // counts + cursor
  router_kernel<<<T_TOK / 4, 256, 0, stream>>>(x, rk, counts, tok_e, tok_w);
  scan_kernel<<<1, 64, 0, stream>>>(counts, offsets, tile_e, tile_mt, ntiles);
  assign_kernel<<<T_TOK / 256, 256, 0, stream>>>(tok_e, tok_w, offsets, cursor,
                                                 slot_token, slot_weight, tok_slot);
  cvt_x_kernel<<<(T_TOK * DIM / 8) / 256, 256, 0, stream>>>(x, xb);
  transpose_cvt_kernel<<<dim3(FDIM / 64, DIM / 64, NEXP), 256, 0, stream>>>(wg_f, wgt, DIM, FDIM);
  transpose_cvt_kernel<<<dim3(FDIM / 64, DIM / 64, NEXP), 256, 0, stream>>>(wu_f, wut, DIM, FDIM);
  transpose_cvt_kernel<<<dim3(DIM / 64, FDIM / 64, NEXP), 256, 0, stream>>>(wd_f, wdt, FDIM, DIM);

  // --- ablation probes (scratch outputs overwritten by real GEMMs below) ---
  probe_stage<<<dim3(16, 32), 256, 0, stream>>>(xb, wgt, wut, slot_token,
                                                (unsigned int*)fuse);
  probe_mfma<<<dim3(16, 32), 256, 0, stream>>>(xb, wgt, wut, slot_token, part);

  gemm_gateup<<<dim3(FDIM / 128, MAXTILE * 40 / 64, 1), 256, 0, stream>>>(
      xb, wgt, wut, counts, offsets, slot_token, tile_e, tile_mt, ntiles, fuse);
  gemm_down<<<dim3(DIM / 128, MAXTILE * 40 / 64, 1), 256, 0, stream>>>(
      fuse, wdt, counts, offsets, slot_weight, tile_e, tile_mt, ntiles, part);
  combine_kernel<<<(T_TOK * DIM / 4) / 256, 256, 0, stream>>>(part, tok_slot, out);
}

// Round 7
// 325.205 us; speedup vs baseline: 1.0549x; 1.0549x over previous
//
#include <hip/hip_runtime.h>
#include <hip/hip_bf16.h>
#include <stdint.h>

#define T_TOK 2048
#define DIM 1024
#define FDIM 2048
#define NEXP 8
#define NSLOT 4096
#define MAXTILE 64

typedef short bf16x8 __attribute__((ext_vector_type(8)));
typedef unsigned short u16x8 __attribute__((ext_vector_type(8)));
typedef float f32x4 __attribute__((ext_vector_type(4)));

__device__ __forceinline__ unsigned short f2bf(float f) {
  union { float f; unsigned int u; } v; v.f = f;
  unsigned int r = v.u + 0x7FFFu + ((v.u >> 16) & 1u);
  return (unsigned short)(r >> 16);
}

__device__ __forceinline__ float bf2f(unsigned short x) {
  union { unsigned int u; float f; } v; v.u = ((unsigned int)x) << 16;
  return v.f;
}

__device__ __forceinline__ void gld_lds16(const void* g, void* l) {
  __builtin_amdgcn_global_load_lds(
      (const __attribute__((address_space(1))) unsigned int*)g,
      (__attribute__((address_space(3))) unsigned int*)l, 16, 0, 0);
}

// ---------------- Router: fp32 exact, one wave per token ----------------
__global__ void router_kernel(const float* __restrict__ x, const float* __restrict__ rk,
                              int* __restrict__ counts, int* __restrict__ tok_e,
                              float* __restrict__ tok_w) {
  int w = threadIdx.x >> 6, lane = threadIdx.x & 63;
  int t = blockIdx.x * 4 + w;
  float acc[NEXP];
#pragma unroll
  for (int e = 0; e < NEXP; ++e) acc[e] = 0.f;
  const float4* xr = (const float4*)(x + (size_t)t * DIM);
#pragma unroll
  for (int i = 0; i < 4; ++i) {
    float4 xv = xr[i * 64 + lane];
    int d0 = (i * 64 + lane) * 4;
#pragma unroll
    for (int j = 0; j < 4; ++j) {
      const float4* rr = (const float4*)(rk + (size_t)(d0 + j) * NEXP);
      float4 r0 = rr[0], r1 = rr[1];
      float xs = (j == 0) ? xv.x : (j == 1) ? xv.y : (j == 2) ? xv.z : xv.w;
      acc[0] += xs * r0.x; acc[1] += xs * r0.y; acc[2] += xs * r0.z; acc[3] += xs * r0.w;
      acc[4] += xs * r1.x; acc[5] += xs * r1.y; acc[6] += xs * r1.z; acc[7] += xs * r1.w;
    }
  }
#pragma unroll
  for (int off = 32; off > 0; off >>= 1) {
#pragma unroll
    for (int e = 0; e < NEXP; ++e) acc[e] += __shfl_xor(acc[e], off, 64);
  }
  if (lane == 0) {
    float m = acc[0];
    for (int e = 1; e < NEXP; ++e) m = fmaxf(m, acc[e]);
    float p[NEXP], s = 0.f;
    for (int e = 0; e < NEXP; ++e) { p[e] = expf(acc[e] - m); s += p[e]; }
    float inv = 1.f / s;
    for (int e = 0; e < NEXP; ++e) p[e] *= inv;
    int i1 = 0;
    for (int e = 1; e < NEXP; ++e) if (p[e] > p[i1]) i1 = e;      // ties -> lowest idx
    int i2 = (i1 == 0) ? 1 : 0;
    for (int e = 0; e < NEXP; ++e) if (e != i1 && p[e] > p[i2]) i2 = e;
    // reference: softmax over the two top PROBABILITIES
    float e1 = expf(p[i1]), e2 = expf(p[i2]);
    float winv = 1.f / (e1 + e2);
    tok_e[t * 2] = i1; tok_e[t * 2 + 1] = i2;
    tok_w[t * 2] = e1 * winv; tok_w[t * 2 + 1] = e2 * winv;
    atomicAdd(&counts[i1], 1); atomicAdd(&counts[i2], 1);
  }
}

__global__ void scan_kernel(const int* __restrict__ counts, int* __restrict__ offsets,
                            int* __restrict__ tile_e, int* __restrict__ tile_mt,
                            int* __restrict__ ntiles) {
  if (threadIdx.x == 0) {
    int s = 0, t = 0;
    for (int e = 0; e < NEXP; ++e) {
      offsets[e] = s; s += counts[e];
      int nt = (counts[e] + 127) >> 7;
      for (int m = 0; m < nt; ++m) { tile_e[t] = e; tile_mt[t] = m; ++t; }
    }
    ntiles[0] = t;
  }
}

__global__ void assign_kernel(const int* __restrict__ tok_e, const float* __restrict__ tok_w,
                              const int* __restrict__ offsets, int* __restrict__ cursor,
                              int* __restrict__ slot_token, float* __restrict__ slot_weight,
                              int* __restrict__ tok_slot) {
  int t = blockIdx.x * 256 + threadIdx.x;
  if (t >= T_TOK) return;
#pragma unroll
  for (int k = 0; k < 2; ++k) {
    int e = tok_e[t * 2 + k];
    int pos = atomicAdd(&cursor[e], 1);
    int slot = offsets[e] + pos;
    slot_token[slot] = t;
    slot_weight[slot] = tok_w[t * 2 + k];
    tok_slot[t * 2 + k] = slot;
  }
}

// ---------------- Conversions ----------------
__global__ void cvt_x_kernel(const float* __restrict__ x, unsigned short* __restrict__ xb) {
  int i = blockIdx.x * 256 + threadIdx.x;  // T*D/8 threads
  const float4* p = (const float4*)x;
  float4 a = p[i * 2], b = p[i * 2 + 1];
  uint4 o;
  o.x = ((unsigned)f2bf(a.y) << 16) | f2bf(a.x);
  o.y = ((unsigned)f2bf(a.w) << 16) | f2bf(a.z);
  o.z = ((unsigned)f2bf(b.y) << 16) | f2bf(b.x);
  o.w = ((unsigned)f2bf(b.w) << 16) | f2bf(b.z);
  ((uint4*)xb)[i] = o;
}

// in fp32 [E][R][C] -> out bf16 [E][C][R]
__global__ void transpose_cvt_kernel(const float* __restrict__ in, unsigned short* __restrict__ out,
                                     int R, int C) {
  __shared__ float lds[64][65];
  int e = blockIdx.z;
  size_t base = (size_t)e * (size_t)R * (size_t)C;
  int rb = blockIdx.y * 64, cb = blockIdx.x * 64;
  int tid = threadIdx.x;
  int col4 = (tid & 15) * 4, row = tid >> 4;
#pragma unroll
  for (int it = 0; it < 4; ++it) {
    int r = row + it * 16;
    float4 v = *(const float4*)(in + base + (size_t)(rb + r) * C + cb + col4);
    lds[col4 + 0][r] = v.x; lds[col4 + 1][r] = v.y;
    lds[col4 + 2][r] = v.z; lds[col4 + 3][r] = v.w;
  }
  __syncthreads();
  int r2 = (tid & 31) * 2, c = tid >> 5;
#pragma unroll
  for (int it = 0; it < 8; ++it) {
    int cc = c + it * 8;
    unsigned v = ((unsigned)f2bf(lds[cc][r2 + 1]) << 16) | f2bf(lds[cc][r2]);
    *(unsigned*)(out + base + (size_t)(cb + cc) * R + rb + r2) = v;
  }
}

// GEMM (round 7): blocks/CU is the measured lever (m102: 320->833 TF at
// 1->4 blocks/CU; rounds 1-6 invariant to everything else). Tiles shrunk to
// 128x64 (gateup 32KB LDS, down 24KB), grids ~1024 real blocks = 4/CU, and
// gemm_down gains split-K x2 with bf16 partials. T2 swizzle kept.

// ---------------- Pass A: fuse[slot][F] = silu(X@Wg) * (X@Wu) ----------------
__global__ __launch_bounds__(256, 4) void gemm_gateup(
    const unsigned short* __restrict__ xb, const unsigned short* __restrict__ wg,
    const unsigned short* __restrict__ wu, const int* __restrict__ counts,
    const int* __restrict__ offsets, const int* __restrict__ slot_token,
    const int* __restrict__ tile_e, const int* __restrict__ tile_mt,
    const int* __restrict__ ntiles, unsigned short* __restrict__ fuse) {
  int ys = blockIdx.y;
  if (ys >= ntiles[0]) return;
  int e = tile_e[ys], mt = tile_mt[ys];
  int cnt = counts[e];
  int off = offsets[e];
  int nt = blockIdx.x;  // 32 tiles of 64 f-cols
  __shared__ unsigned short Al[128 * 64];
  __shared__ unsigned short Bgl[64 * 64];
  __shared__ unsigned short Bul[64 * 64];
  int tid = threadIdx.x, w = tid >> 6, lane = tid & 63;
  int csrc = ((lane & 7) ^ (lane >> 3)) * 8;  // swizzled source chunk (bf16 elems)
  const unsigned short* asrc[4];
  const unsigned short* bgsrc[2];
  const unsigned short* busrc[2];
#pragma unroll
  for (int ii = 0; ii < 4; ++ii) {
    int r = (w * 4 + ii) * 8 + (lane >> 3);
    int row = mt * 128 + r;
    int tok = (row < cnt) ? slot_token[off + row] : 0;  // clamp: garbage rows computed, not written
    asrc[ii] = xb + (size_t)tok * DIM + csrc;
  }
#pragma unroll
  for (int ii = 0; ii < 2; ++ii) {
    int r = (w * 2 + ii) * 8 + (lane >> 3);
    size_t frow = (size_t)e * FDIM + (size_t)(nt * 64 + r);
    bgsrc[ii] = wg + frow * DIM + csrc;
    busrc[ii] = wu + frow * DIM + csrc;
  }
  f32x4 accg[4][2] = {};
  f32x4 accu[4][2] = {};
  int wr = (w >> 1) * 64, wc = (w & 1) * 32;
  int swz = (lane & 7) << 3;
  int kof0 = ((lane >> 4) * 8) ^ swz;        // kk=0 swizzled col offset
  int kof1 = (32 + (lane >> 4) * 8) ^ swz;   // kk=1
  for (int k0 = 0; k0 < DIM; k0 += 64) {
#pragma unroll
    for (int ii = 0; ii < 4; ++ii)
      gld_lds16(asrc[ii] + k0, &Al[(w * 4 + ii) * 512]);
#pragma unroll
    for (int ii = 0; ii < 2; ++ii) {
      gld_lds16(bgsrc[ii] + k0, &Bgl[(w * 2 + ii) * 512]);
      gld_lds16(busrc[ii] + k0, &Bul[(w * 2 + ii) * 512]);
    }
    __syncthreads();
#pragma unroll
    for (int kk = 0; kk < 2; ++kk) {
      int kof = kk ? kof1 : kof0;
      bf16x8 af[4], bg[2], bu[2];
#pragma unroll
      for (int q = 0; q < 4; ++q)
        af[q] = *(const bf16x8*)&Al[(wr + q * 16 + (lane & 15)) * 64 + kof];
#pragma unroll
      for (int q = 0; q < 2; ++q) {
        bg[q] = *(const bf16x8*)&Bgl[(wc + q * 16 + (lane & 15)) * 64 + kof];
        bu[q] = *(const bf16x8*)&Bul[(wc + q * 16 + (lane & 15)) * 64 + kof];
      }
#pragma unroll
      for (int m4 = 0; m4 < 4; ++m4) {
#pragma unroll
        for (int n4 = 0; n4 < 2; ++n4) {
          accg[m4][n4] = __builtin_amdgcn_mfma_f32_16x16x32_bf16(af[m4], bg[n4], accg[m4][n4], 0, 0, 0);
          accu[m4][n4] = __builtin_amdgcn_mfma_f32_16x16x32_bf16(af[m4], bu[n4], accu[m4][n4], 0, 0, 0);
        }
      }
    }
    __syncthreads();
  }
#pragma unroll
  for (int m4 = 0; m4 < 4; ++m4) {
#pragma unroll
    for (int n4 = 0; n4 < 2; ++n4) {
      f32x4 g = accg[m4][n4], u = accu[m4][n4];
#pragma unroll
      for (int j = 0; j < 4; ++j) {
        int r = wr + m4 * 16 + (lane >> 4) * 4 + j;  // C layout: row=(lane>>4)*4+reg
        int row = mt * 128 + r;
        if (row < cnt) {
          float gv = g[j];
          float val = gv / (1.f + expf(-gv)) * u[j];
          int f = nt * 64 + wc + n4 * 16 + (lane & 15);  // col=lane&15
          fuse[(size_t)(off + row) * FDIM + f] = f2bf(val);
        }
      }
    }
  }
}

// ---------------- Pass B: part2[z][slot][D] = w_slot * (fuse[:,zK:(z+1)K] @ WdT) ----------------
__global__ __launch_bounds__(256, 4) void gemm_down(
    const unsigned short* __restrict__ fuse, const unsigned short* __restrict__ wd,
    const int* __restrict__ counts, const int* __restrict__ offsets,
    const float* __restrict__ slot_weight, const int* __restrict__ tile_e,
    const int* __restrict__ tile_mt, const int* __restrict__ ntiles,
    unsigned short* __restrict__ part2) {
  int ys = blockIdx.y;
  if (ys >= ntiles[0]) return;
  int e = tile_e[ys], mt = tile_mt[ys];
  int cnt = counts[e];
  int off = offsets[e];
  int nt = blockIdx.x;   // 16 tiles of 64 d-cols
  int z = blockIdx.z;    // split-K half
  int kbase = z * (FDIM / 2);
  __shared__ unsigned short Al[128 * 64];
  __shared__ unsigned short Bl[64 * 64];
  int tid = threadIdx.x, w = tid >> 6, lane = tid & 63;
  int csrc = ((lane & 7) ^ (lane >> 3)) * 8;
  const unsigned short* asrc[4];
  const unsigned short* bsrc[2];
#pragma unroll
  for (int ii = 0; ii < 4; ++ii) {
    int r = (w * 4 + ii) * 8 + (lane >> 3);
    int row = mt * 128 + r;
    int grow = (row < cnt) ? (off + row) : off;  // clamp to valid memory
    asrc[ii] = fuse + (size_t)grow * FDIM + kbase + csrc;
  }
#pragma unroll
  for (int ii = 0; ii < 2; ++ii) {
    int r = (w * 2 + ii) * 8 + (lane >> 3);
    size_t drow = (size_t)e * DIM + (size_t)(nt * 64 + r);
    bsrc[ii] = wd + drow * FDIM + kbase + csrc;
  }
  f32x4 acc[4][2] = {};
  int wr = (w >> 1) * 64, wc = (w & 1) * 32;
  int swz = (lane & 7) << 3;
  int kof0 = ((lane >> 4) * 8) ^ swz;
  int kof1 = (32 + (lane >> 4) * 8) ^ swz;
  for (int k0 = 0; k0 < FDIM / 2; k0 += 64) {
#pragma unroll
    for (int ii = 0; ii < 4; ++ii)
      gld_lds16(asrc[ii] + k0, &Al[(w * 4 + ii) * 512]);
#pragma unroll
    for (int ii = 0; ii < 2; ++ii)
      gld_lds16(bsrc[ii] + k0, &Bl[(w * 2 + ii) * 512]);
    __syncthreads();
#pragma unroll
    for (int kk = 0; kk < 2; ++kk) {
      int kof = kk ? kof1 : kof0;
      bf16x8 af[4], bfr[2];
#pragma unroll
      for (int q = 0; q < 4; ++q)
        af[q] = *(const bf16x8*)&Al[(wr + q * 16 + (lane & 15)) * 64 + kof];
#pragma unroll
      for (int q = 0; q < 2; ++q)
        bfr[q] = *(const bf16x8*)&Bl[(wc + q * 16 + (lane & 15)) * 64 + kof];
#pragma unroll
      for (int m4 = 0; m4 < 4; ++m4) {
#pragma unroll
        for (int n4 = 0; n4 < 2; ++n4) {
          acc[m4][n4] = __builtin_amdgcn_mfma_f32_16x16x32_bf16(af[m4], bfr[n4], acc[m4][n4], 0, 0, 0);
        }
      }
    }
    __syncthreads();
  }
#pragma unroll
  for (int m4 = 0; m4 < 4; ++m4) {
#pragma unroll
    for (int j = 0; j < 4; ++j) {
      int r = wr + m4 * 16 + (lane >> 4) * 4 + j;
      int row = mt * 128 + r;
      if (row < cnt) {
        float wgt = slot_weight[off + row];
#pragma unroll
        for (int n4 = 0; n4 < 2; ++n4) {
          int d = nt * 64 + wc + n4 * 16 + (lane & 15);
          part2[((size_t)z * NSLOT + off + row) * DIM + d] = f2bf(acc[m4][n4][j] * wgt);
        }
      }
    }
  }
}

// ---------------- Combine: out[t] = sum over {slot0,slot1} x {split0,split1} ----------------
__global__ void combine_kernel(const unsigned short* __restrict__ part2,
                               const int* __restrict__ tok_slot, float* __restrict__ out) {
  int i = blockIdx.x * 256 + threadIdx.x;  // T*D/8 threads
  int t = i >> 7;
  int c = i & 127;  // 8-elem chunk within the D=1024 row
  int s0 = tok_slot[t * 2], s1 = tok_slot[t * 2 + 1];
  const u16x8* base = (const u16x8*)part2;
  u16x8 a0 = base[((size_t)s0) * (DIM / 8) + c];
  u16x8 a1 = base[((size_t)NSLOT + s0) * (DIM / 8) + c];
  u16x8 b0 = base[((size_t)s1) * (DIM / 8) + c];
  u16x8 b1 = base[((size_t)NSLOT + s1) * (DIM / 8) + c];
  float o[8];
#pragma unroll
  for (int j = 0; j < 8; ++j)
    o[j] = (bf2f(a0[j]) + bf2f(a1[j])) + (bf2f(b0[j]) + bf2f(b1[j]));
  float4* dst = (float4*)(out + (size_t)t * DIM + c * 8);
  dst[0] = make_float4(o[0], o[1], o[2], o[3]);
  dst[1] = make_float4(o[4], o[5], o[6], o[7]);
}

extern "C" void kernel_launch(void* const* d_in, const int* in_sizes, int n_in,
                              void* d_out, int out_size, void* d_ws, size_t ws_size,
                              hipStream_t stream) {
  (void)in_sizes; (void)n_in; (void)out_size;
  const float* x    = (const float*)d_in[0];
  const float* rk   = (const float*)d_in[1];
  const float* wg_f = (const float*)d_in[2];
  const float* wu_f = (const float*)d_in[3];
  const float* wd_f = (const float*)d_in[4];
  float* out = (float*)d_out;

  char* ws = (char*)d_ws;
  size_t o_xb   = 0;
  size_t o_wg   = o_xb + (size_t)T_TOK * DIM * 2;
  size_t o_wu   = o_wg + (size_t)NEXP * FDIM * DIM * 2;
  size_t o_wd   = o_wu + (size_t)NEXP * FDIM * DIM * 2;
  size_t o_fuse = o_wd + (size_t)NEXP * DIM * FDIM * 2;
  size_t o_part = o_fuse + (size_t)NSLOT * FDIM * 2;      // part2: 2 x NSLOT x DIM bf16
  size_t o_meta = o_part + (size_t)2 * NSLOT * DIM * 2;
  size_t o_counts = o_meta;
  size_t o_cursor = o_counts + 32;
  size_t o_offs   = o_cursor + 32;
  size_t o_tok_e  = o_offs + 32;
  size_t o_tok_w  = o_tok_e + (size_t)T_TOK * 2 * 4;
  size_t o_tok_s  = o_tok_w + (size_t)T_TOK * 2 * 4;
  size_t o_st     = o_tok_s + (size_t)T_TOK * 2 * 4;
  size_t o_sw     = o_st + (size_t)NSLOT * 4;
  size_t o_te     = o_sw + (size_t)NSLOT * 4;
  size_t o_tm     = o_te + MAXTILE * 4;
  size_t o_ntl    = o_tm + MAXTILE * 4;
  size_t need     = o_ntl + 32;
  if (ws_size < need) return;  // diagnostic: absmax will equal ~0.785 (zero output)

  unsigned short* xb    = (unsigned short*)(ws + o_xb);
  unsigned short* wgt   = (unsigned short*)(ws + o_wg);
  unsigned short* wut   = (unsigned short*)(ws + o_wu);
  unsigned short* wdt   = (unsigned short*)(ws + o_wd);
  unsigned short* fuse  = (unsigned short*)(ws + o_fuse);
  unsigned short* part2 = (unsigned short*)(ws + o_part);
  int* counts          = (int*)(ws + o_counts);
  int* cursor          = (int*)(ws + o_cursor);
  int* offsets         = (int*)(ws + o_offs);
  int* tok_e           = (int*)(ws + o_tok_e);
  float* tok_w         = (float*)(ws + o_tok_w);
  int* tok_slot        = (int*)(ws + o_tok_s);
  int* slot_token      = (int*)(ws + o_st);
  float* slot_weight   = (float*)(ws + o_sw);
  int* tile_e          = (int*)(ws + o_te);
  int* tile_mt         = (int*)(ws + o_tm);
  int* ntiles          = (int*)(ws + o_ntl);

  hipMemsetAsync(ws + o_counts, 0, 64, stream);  // counts + cursor
  router_kernel<<<T_TOK / 4, 256, 0, stream>>>(x, rk, counts, tok_e, tok_w);
  scan_kernel<<<1, 64, 0, stream>>>(counts, offsets, tile_e, tile_mt, ntiles);
  assign_kernel<<<T_TOK / 256, 256, 0, stream>>>(tok_e, tok_w, offsets, cursor,
                                                 slot_token, slot_weight, tok_slot);
  cvt_x_kernel<<<(T_TOK * DIM / 8) / 256, 256, 0, stream>>>(x, xb);
  transpose_cvt_kernel<<<dim3(FDIM / 64, DIM / 64, NEXP), 256, 0, stream>>>(wg_f, wgt, DIM, FDIM);
  transpose_cvt_kernel<<<dim3(FDIM / 64, DIM / 64, NEXP), 256, 0, stream>>>(wu_f, wut, DIM, FDIM);
  transpose_cvt_kernel<<<dim3(DIM / 64, FDIM / 64, NEXP), 256, 0, stream>>>(wd_f, wdt, FDIM, DIM);

  gemm_gateup<<<dim3(FDIM / 64, 40, 1), 256, 0, stream>>>(
      xb, wgt, wut, counts, offsets, slot_token, tile_e, tile_mt, ntiles, fuse);
  gemm_down<<<dim3(DIM / 64, 40, 2), 256, 0, stream>>>(
      fuse, wdt, counts, offsets, slot_weight, tile_e, tile_mt, ntiles, part2);
  combine_kernel<<<(T_TOK * DIM / 8) / 256, 256, 0, stream>>>(part2, tok_slot, out);
}

// Round 8
// 260.222 us; speedup vs baseline: 1.3183x; 1.2497x over previous
//
#include <hip/hip_runtime.h>
#include <hip/hip_bf16.h>
#include <stdint.h>

#define T_TOK 2048
#define DIM 1024
#define FDIM 2048
#define NEXP 8
#define NSLOT 4096
#define MAXTILE 64

typedef short bf16x8 __attribute__((ext_vector_type(8)));
typedef unsigned short u16x8 __attribute__((ext_vector_type(8)));
typedef float f32x4 __attribute__((ext_vector_type(4)));

__device__ __forceinline__ unsigned short f2bf(float f) {
  union { float f; unsigned int u; } v; v.f = f;
  unsigned int r = v.u + 0x7FFFu + ((v.u >> 16) & 1u);
  return (unsigned short)(r >> 16);
}

__device__ __forceinline__ float bf2f(unsigned short x) {
  union { unsigned int u; float f; } v; v.u = ((unsigned int)x) << 16;
  return v.f;
}

__device__ __forceinline__ void gld_lds16(const void* g, void* l) {
  __builtin_amdgcn_global_load_lds(
      (const __attribute__((address_space(1))) unsigned int*)g,
      (__attribute__((address_space(3))) unsigned int*)l, 16, 0, 0);
}

// ---------------- Router: fp32 exact, one wave per token ----------------
__global__ void router_kernel(const float* __restrict__ x, const float* __restrict__ rk,
                              int* __restrict__ counts, int* __restrict__ tok_e,
                              float* __restrict__ tok_w) {
  int w = threadIdx.x >> 6, lane = threadIdx.x & 63;
  int t = blockIdx.x * 4 + w;
  float acc[NEXP];
#pragma unroll
  for (int e = 0; e < NEXP; ++e) acc[e] = 0.f;
  const float4* xr = (const float4*)(x + (size_t)t * DIM);
#pragma unroll
  for (int i = 0; i < 4; ++i) {
    float4 xv = xr[i * 64 + lane];
    int d0 = (i * 64 + lane) * 4;
#pragma unroll
    for (int j = 0; j < 4; ++j) {
      const float4* rr = (const float4*)(rk + (size_t)(d0 + j) * NEXP);
      float4 r0 = rr[0], r1 = rr[1];
      float xs = (j == 0) ? xv.x : (j == 1) ? xv.y : (j == 2) ? xv.z : xv.w;
      acc[0] += xs * r0.x; acc[1] += xs * r0.y; acc[2] += xs * r0.z; acc[3] += xs * r0.w;
      acc[4] += xs * r1.x; acc[5] += xs * r1.y; acc[6] += xs * r1.z; acc[7] += xs * r1.w;
    }
  }
#pragma unroll
  for (int off = 32; off > 0; off >>= 1) {
#pragma unroll
    for (int e = 0; e < NEXP; ++e) acc[e] += __shfl_xor(acc[e], off, 64);
  }
  if (lane == 0) {
    float m = acc[0];
    for (int e = 1; e < NEXP; ++e) m = fmaxf(m, acc[e]);
    float p[NEXP], s = 0.f;
    for (int e = 0; e < NEXP; ++e) { p[e] = expf(acc[e] - m); s += p[e]; }
    float inv = 1.f / s;
    for (int e = 0; e < NEXP; ++e) p[e] *= inv;
    int i1 = 0;
    for (int e = 1; e < NEXP; ++e) if (p[e] > p[i1]) i1 = e;      // ties -> lowest idx
    int i2 = (i1 == 0) ? 1 : 0;
    for (int e = 0; e < NEXP; ++e) if (e != i1 && p[e] > p[i2]) i2 = e;
    // reference: softmax over the two top PROBABILITIES
    float e1 = expf(p[i1]), e2 = expf(p[i2]);
    float winv = 1.f / (e1 + e2);
    tok_e[t * 2] = i1; tok_e[t * 2 + 1] = i2;
    tok_w[t * 2] = e1 * winv; tok_w[t * 2 + 1] = e2 * winv;
    atomicAdd(&counts[i1], 1); atomicAdd(&counts[i2], 1);
  }
}

__global__ void scan_kernel(const int* __restrict__ counts, int* __restrict__ offsets,
                            int* __restrict__ tile_e, int* __restrict__ tile_mt,
                            int* __restrict__ ntiles) {
  if (threadIdx.x == 0) {
    int s = 0, t = 0;
    for (int e = 0; e < NEXP; ++e) {
      offsets[e] = s; s += counts[e];
      int nt = (counts[e] + 127) >> 7;
      for (int m = 0; m < nt; ++m) { tile_e[t] = e; tile_mt[t] = m; ++t; }
    }
    ntiles[0] = t;
  }
}

__global__ void assign_kernel(const int* __restrict__ tok_e, const float* __restrict__ tok_w,
                              const int* __restrict__ offsets, int* __restrict__ cursor,
                              int* __restrict__ slot_token, float* __restrict__ slot_weight,
                              int* __restrict__ tok_slot) {
  int t = blockIdx.x * 256 + threadIdx.x;
  if (t >= T_TOK) return;
#pragma unroll
  for (int k = 0; k < 2; ++k) {
    int e = tok_e[t * 2 + k];
    int pos = atomicAdd(&cursor[e], 1);
    int slot = offsets[e] + pos;
    slot_token[slot] = t;
    slot_weight[slot] = tok_w[t * 2 + k];
    tok_slot[t * 2 + k] = slot;
  }
}

// ---------------- Conversions ----------------
__global__ void cvt_x_kernel(const float* __restrict__ x, unsigned short* __restrict__ xb) {
  int i = blockIdx.x * 256 + threadIdx.x;  // T*D/8 threads
  const float4* p = (const float4*)x;
  float4 a = p[i * 2], b = p[i * 2 + 1];
  uint4 o;
  o.x = ((unsigned)f2bf(a.y) << 16) | f2bf(a.x);
  o.y = ((unsigned)f2bf(a.w) << 16) | f2bf(a.z);
  o.z = ((unsigned)f2bf(b.y) << 16) | f2bf(b.x);
  o.w = ((unsigned)f2bf(b.w) << 16) | f2bf(b.z);
  ((uint4*)xb)[i] = o;
}

// in fp32 [E][R][C] -> out bf16 [E][C][R]
__global__ void transpose_cvt_kernel(const float* __restrict__ in, unsigned short* __restrict__ out,
                                     int R, int C) {
  __shared__ float lds[64][65];
  int e = blockIdx.z;
  size_t base = (size_t)e * (size_t)R * (size_t)C;
  int rb = blockIdx.y * 64, cb = blockIdx.x * 64;
  int tid = threadIdx.x;
  int col4 = (tid & 15) * 4, row = tid >> 4;
#pragma unroll
  for (int it = 0; it < 4; ++it) {
    int r = row + it * 16;
    float4 v = *(const float4*)(in + base + (size_t)(rb + r) * C + cb + col4);
    lds[col4 + 0][r] = v.x; lds[col4 + 1][r] = v.y;
    lds[col4 + 2][r] = v.z; lds[col4 + 3][r] = v.w;
  }
  __syncthreads();
  int r2 = (tid & 31) * 2, c = tid >> 5;
#pragma unroll
  for (int it = 0; it < 8; ++it) {
    int cc = c + it * 8;
    unsigned v = ((unsigned)f2bf(lds[cc][r2 + 1]) << 16) | f2bf(lds[cc][r2]);
    *(unsigned*)(out + base + (size_t)(cb + cc) * R + rb + r2) = v;
  }
}

// GEMM (round 8): r7 proved 4 blocks/CU engages (occupancy 8.5->34%, HBM
// 2.8TB/s) but __launch_bounds__(256,4) clamped VGPR to 64 vs ~110 working
// set -> 400MB/dispatch scratch spills. Fix: no min-waves clamp (compiler
// lands ~110<=128 -> 4 waves/SIMD naturally) + 32-bit element offsets off
// SGPR bases instead of 64-bit per-lane pointers.

// ---------------- Pass A: fuse[slot][F] = silu(X@Wg) * (X@Wu) ----------------
__global__ __launch_bounds__(256) void gemm_gateup(
    const unsigned short* __restrict__ xb, const unsigned short* __restrict__ wg,
    const unsigned short* __restrict__ wu, const int* __restrict__ counts,
    const int* __restrict__ offsets, const int* __restrict__ slot_token,
    const int* __restrict__ tile_e, const int* __restrict__ tile_mt,
    const int* __restrict__ ntiles, unsigned short* __restrict__ fuse) {
  int ys = blockIdx.y;
  if (ys >= ntiles[0]) return;
  int e = tile_e[ys], mt = tile_mt[ys];
  int cnt = counts[e];
  int off = offsets[e];
  int nt = blockIdx.x;  // 32 tiles of 64 f-cols
  __shared__ unsigned short Al[128 * 64];
  __shared__ unsigned short Bgl[64 * 64];
  __shared__ unsigned short Bul[64 * 64];
  int tid = threadIdx.x, w = tid >> 6, lane = tid & 63;
  int csrc = ((lane & 7) ^ (lane >> 3)) * 8;  // swizzled source chunk (bf16 elems)
  unsigned aoff[4];   // 32-bit element offsets (save VGPRs vs 64-bit ptrs)
  unsigned boff[2];   // same row offset for wg and wu
#pragma unroll
  for (int ii = 0; ii < 4; ++ii) {
    int r = (w * 4 + ii) * 8 + (lane >> 3);
    int row = mt * 128 + r;
    int tok = (row < cnt) ? slot_token[off + row] : 0;  // clamp: garbage rows computed, not written
    aoff[ii] = (unsigned)(tok * DIM + csrc);
  }
#pragma unroll
  for (int ii = 0; ii < 2; ++ii) {
    int r = (w * 2 + ii) * 8 + (lane >> 3);
    boff[ii] = (unsigned)((e * FDIM + nt * 64 + r) * DIM + csrc);
  }
  f32x4 accg[4][2] = {};
  f32x4 accu[4][2] = {};
  int wr = (w >> 1) * 64, wc = (w & 1) * 32;
  int swz = (lane & 7) << 3;
  int kof0 = ((lane >> 4) * 8) ^ swz;        // kk=0 swizzled col offset
  int kof1 = (32 + (lane >> 4) * 8) ^ swz;   // kk=1
  for (int k0 = 0; k0 < DIM; k0 += 64) {
#pragma unroll
    for (int ii = 0; ii < 4; ++ii)
      gld_lds16(xb + aoff[ii] + k0, &Al[(w * 4 + ii) * 512]);
#pragma unroll
    for (int ii = 0; ii < 2; ++ii) {
      gld_lds16(wg + boff[ii] + k0, &Bgl[(w * 2 + ii) * 512]);
      gld_lds16(wu + boff[ii] + k0, &Bul[(w * 2 + ii) * 512]);
    }
    __syncthreads();
#pragma unroll
    for (int kk = 0; kk < 2; ++kk) {
      int kof = kk ? kof1 : kof0;
      bf16x8 af[4], bg[2], bu[2];
#pragma unroll
      for (int q = 0; q < 4; ++q)
        af[q] = *(const bf16x8*)&Al[(wr + q * 16 + (lane & 15)) * 64 + kof];
#pragma unroll
      for (int q = 0; q < 2; ++q) {
        bg[q] = *(const bf16x8*)&Bgl[(wc + q * 16 + (lane & 15)) * 64 + kof];
        bu[q] = *(const bf16x8*)&Bul[(wc + q * 16 + (lane & 15)) * 64 + kof];
      }
#pragma unroll
      for (int m4 = 0; m4 < 4; ++m4) {
#pragma unroll
        for (int n4 = 0; n4 < 2; ++n4) {
          accg[m4][n4] = __builtin_amdgcn_mfma_f32_16x16x32_bf16(af[m4], bg[n4], accg[m4][n4], 0, 0, 0);
          accu[m4][n4] = __builtin_amdgcn_mfma_f32_16x16x32_bf16(af[m4], bu[n4], accu[m4][n4], 0, 0, 0);
        }
      }
    }
    __syncthreads();
  }
#pragma unroll
  for (int m4 = 0; m4 < 4; ++m4) {
#pragma unroll
    for (int n4 = 0; n4 < 2; ++n4) {
      f32x4 g = accg[m4][n4], u = accu[m4][n4];
#pragma unroll
      for (int j = 0; j < 4; ++j) {
        int r = wr + m4 * 16 + (lane >> 4) * 4 + j;  // C layout: row=(lane>>4)*4+reg
        int row = mt * 128 + r;
        if (row < cnt) {
          float gv = g[j];
          float val = gv / (1.f + expf(-gv)) * u[j];
          int f = nt * 64 + wc + n4 * 16 + (lane & 15);  // col=lane&15
          fuse[(size_t)(off + row) * FDIM + f] = f2bf(val);
        }
      }
    }
  }
}

// ---------------- Pass B: part2[z][slot][D] = w_slot * (fuse[:,zK:(z+1)K] @ WdT) ----------------
__global__ __launch_bounds__(256) void gemm_down(
    const unsigned short* __restrict__ fuse, const unsigned short* __restrict__ wd,
    const int* __restrict__ counts, const int* __restrict__ offsets,
    const float* __restrict__ slot_weight, const int* __restrict__ tile_e,
    const int* __restrict__ tile_mt, const int* __restrict__ ntiles,
    unsigned short* __restrict__ part2) {
  int ys = blockIdx.y;
  if (ys >= ntiles[0]) return;
  int e = tile_e[ys], mt = tile_mt[ys];
  int cnt = counts[e];
  int off = offsets[e];
  int nt = blockIdx.x;   // 16 tiles of 64 d-cols
  int z = blockIdx.z;    // split-K half
  int kbase = z * (FDIM / 2);
  __shared__ unsigned short Al[128 * 64];
  __shared__ unsigned short Bl[64 * 64];
  int tid = threadIdx.x, w = tid >> 6, lane = tid & 63;
  int csrc = ((lane & 7) ^ (lane >> 3)) * 8;
  unsigned aoff[4];
  unsigned boff[2];
#pragma unroll
  for (int ii = 0; ii < 4; ++ii) {
    int r = (w * 4 + ii) * 8 + (lane >> 3);
    int row = mt * 128 + r;
    int grow = (row < cnt) ? (off + row) : off;  // clamp to valid memory
    aoff[ii] = (unsigned)(grow * FDIM + kbase + csrc);
  }
#pragma unroll
  for (int ii = 0; ii < 2; ++ii) {
    int r = (w * 2 + ii) * 8 + (lane >> 3);
    boff[ii] = (unsigned)((e * DIM + nt * 64 + r) * FDIM + kbase + csrc);
  }
  f32x4 acc[4][2] = {};
  int wr = (w >> 1) * 64, wc = (w & 1) * 32;
  int swz = (lane & 7) << 3;
  int kof0 = ((lane >> 4) * 8) ^ swz;
  int kof1 = (32 + (lane >> 4) * 8) ^ swz;
  for (int k0 = 0; k0 < FDIM / 2; k0 += 64) {
#pragma unroll
    for (int ii = 0; ii < 4; ++ii)
      gld_lds16(fuse + aoff[ii] + k0, &Al[(w * 4 + ii) * 512]);
#pragma unroll
    for (int ii = 0; ii < 2; ++ii)
      gld_lds16(wd + boff[ii] + k0, &Bl[(w * 2 + ii) * 512]);
    __syncthreads();
#pragma unroll
    for (int kk = 0; kk < 2; ++kk) {
      int kof = kk ? kof1 : kof0;
      bf16x8 af[4], bfr[2];
#pragma unroll
      for (int q = 0; q < 4; ++q)
        af[q] = *(const bf16x8*)&Al[(wr + q * 16 + (lane & 15)) * 64 + kof];
#pragma unroll
      for (int q = 0; q < 2; ++q)
        bfr[q] = *(const bf16x8*)&Bl[(wc + q * 16 + (lane & 15)) * 64 + kof];
#pragma unroll
      for (int m4 = 0; m4 < 4; ++m4) {
#pragma unroll
        for (int n4 = 0; n4 < 2; ++n4) {
          acc[m4][n4] = __builtin_amdgcn_mfma_f32_16x16x32_bf16(af[m4], bfr[n4], acc[m4][n4], 0, 0, 0);
        }
      }
    }
    __syncthreads();
  }
#pragma unroll
  for (int m4 = 0; m4 < 4; ++m4) {
#pragma unroll
    for (int j = 0; j < 4; ++j) {
      int r = wr + m4 * 16 + (lane >> 4) * 4 + j;
      int row = mt * 128 + r;
      if (row < cnt) {
        float wgt = slot_weight[off + row];
#pragma unroll
        for (int n4 = 0; n4 < 2; ++n4) {
          int d = nt * 64 + wc + n4 * 16 + (lane & 15);
          part2[((size_t)z * NSLOT + off + row) * DIM + d] = f2bf(acc[m4][n4][j] * wgt);
        }
      }
    }
  }
}

// ---------------- Combine: out[t] = sum over {slot0,slot1} x {split0,split1} ----------------
__global__ void combine_kernel(const unsigned short* __restrict__ part2,
                               const int* __restrict__ tok_slot, float* __restrict__ out) {
  int i = blockIdx.x * 256 + threadIdx.x;  // T*D/8 threads
  int t = i >> 7;
  int c = i & 127;  // 8-elem chunk within the D=1024 row
  int s0 = tok_slot[t * 2], s1 = tok_slot[t * 2 + 1];
  const u16x8* base = (const u16x8*)part2;
  u16x8 a0 = base[((size_t)s0) * (DIM / 8) + c];
  u16x8 a1 = base[((size_t)NSLOT + s0) * (DIM / 8) + c];
  u16x8 b0 = base[((size_t)s1) * (DIM / 8) + c];
  u16x8 b1 = base[((size_t)NSLOT + s1) * (DIM / 8) + c];
  float o[8];
#pragma unroll
  for (int j = 0; j < 8; ++j)
    o[j] = (bf2f(a0[j]) + bf2f(a1[j])) + (bf2f(b0[j]) + bf2f(b1[j]));
  float4* dst = (float4*)(out + (size_t)t * DIM + c * 8);
  dst[0] = make_float4(o[0], o[1], o[2], o[3]);
  dst[1] = make_float4(o[4], o[5], o[6], o[7]);
}

extern "C" void kernel_launch(void* const* d_in, const int* in_sizes, int n_in,
                              void* d_out, int out_size, void* d_ws, size_t ws_size,
                              hipStream_t stream) {
  (void)in_sizes; (void)n_in; (void)out_size;
  const float* x    = (const float*)d_in[0];
  const float* rk   = (const float*)d_in[1];
  const float* wg_f = (const float*)d_in[2];
  const float* wu_f = (const float*)d_in[3];
  const float* wd_f = (const float*)d_in[4];
  float* out = (float*)d_out;

  char* ws = (char*)d_ws;
  size_t o_xb   = 0;
  size_t o_wg   = o_xb + (size_t)T_TOK * DIM * 2;
  size_t o_wu   = o_wg + (size_t)NEXP * FDIM * DIM * 2;
  size_t o_wd   = o_wu + (size_t)NEXP * FDIM * DIM * 2;
  size_t o_fuse = o_wd + (size_t)NEXP * DIM * FDIM * 2;
  size_t o_part = o_fuse + (size_t)NSLOT * FDIM * 2;      // part2: 2 x NSLOT x DIM bf16
  size_t o_meta = o_part + (size_t)2 * NSLOT * DIM * 2;
  size_t o_counts = o_meta;
  size_t o_cursor = o_counts + 32;
  size_t o_offs   = o_cursor + 32;
  size_t o_tok_e  = o_offs + 32;
  size_t o_tok_w  = o_tok_e + (size_t)T_TOK * 2 * 4;
  size_t o_tok_s  = o_tok_w + (size_t)T_TOK * 2 * 4;
  size_t o_st     = o_tok_s + (size_t)T_TOK * 2 * 4;
  size_t o_sw     = o_st + (size_t)NSLOT * 4;
  size_t o_te     = o_sw + (size_t)NSLOT * 4;
  size_t o_tm     = o_te + MAXTILE * 4;
  size_t o_ntl    = o_tm + MAXTILE * 4;
  size_t need     = o_ntl + 32;
  if (ws_size < need) return;  // diagnostic: absmax will equal ~0.785 (zero output)

  unsigned short* xb    = (unsigned short*)(ws + o_xb);
  unsigned short* wgt   = (unsigned short*)(ws + o_wg);
  unsigned short* wut   = (unsigned short*)(ws + o_wu);
  unsigned short* wdt   = (unsigned short*)(ws + o_wd);
  unsigned short* fuse  = (unsigned short*)(ws + o_fuse);
  unsigned short* part2 = (unsigned short*)(ws + o_part);
  int* counts          = (int*)(ws + o_counts);
  int* cursor          = (int*)(ws + o_cursor);
  int* offsets         = (int*)(ws + o_offs);
  int* tok_e           = (int*)(ws + o_tok_e);
  float* tok_w         = (float*)(ws + o_tok_w);
  int* tok_slot        = (int*)(ws + o_tok_s);
  int* slot_token      = (int*)(ws + o_st);
  float* slot_weight   = (float*)(ws + o_sw);
  int* tile_e          = (int*)(ws + o_te);
  int* tile_mt         = (int*)(ws + o_tm);
  int* ntiles          = (int*)(ws + o_ntl);

  hipMemsetAsync(ws + o_counts, 0, 64, stream);  // counts + cursor
  router_kernel<<<T_TOK / 4, 256, 0, stream>>>(x, rk, counts, tok_e, tok_w);
  scan_kernel<<<1, 64, 0, stream>>>(counts, offsets, tile_e, tile_mt, ntiles);
  assign_kernel<<<T_TOK / 256, 256, 0, stream>>>(tok_e, tok_w, offsets, cursor,
                                                 slot_token, slot_weight, tok_slot);
  cvt_x_kernel<<<(T_TOK * DIM / 8) / 256, 256, 0, stream>>>(x, xb);
  transpose_cvt_kernel<<<dim3(FDIM / 64, DIM / 64, NEXP), 256, 0, stream>>>(wg_f, wgt, DIM, FDIM);
  transpose_cvt_kernel<<<dim3(FDIM / 64, DIM / 64, NEXP), 256, 0, stream>>>(wu_f, wut, DIM, FDIM);
  transpose_cvt_kernel<<<dim3(DIM / 64, FDIM / 64, NEXP), 256, 0, stream>>>(wd_f, wdt, FDIM, DIM);

  gemm_gateup<<<dim3(FDIM / 64, 40, 1), 256, 0, stream>>>(
      xb, wgt, wut, counts, offsets, slot_token, tile_e, tile_mt, ntiles, fuse);
  gemm_down<<<dim3(DIM / 64, 40, 2), 256, 0, stream>>>(
      fuse, wdt, counts, offsets, slot_weight, tile_e, tile_mt, ntiles, part2);
  combine_kernel<<<(T_TOK * DIM / 8) / 256, 256, 0, stream>>>(part2, tok_slot, out);
}